// Round 1
// baseline (135.068 us; speedup 1.0000x reference)
//
#include <hip/hip_runtime.h>

#define PTOT 200000
#define NB 512
#define DD 64
#define PT 256
#define NBLK ((PTOT + PT - 1) / PT)   /* 782 */
#define NCAND 8

typedef __attribute__((ext_vector_type(4))) float f32x4;
typedef __attribute__((ext_vector_type(8))) __bf16 bf16x8;

__device__ __forceinline__ ushort f2bf(float f){
  uint u = __float_as_uint(f);
  u += 0x7FFFu + ((u >> 16) & 1u);
  return (ushort)(u >> 16);
}

// monotonic sortable key: f32 sim with low 9 mantissa bits replaced by local idx
__device__ __forceinline__ uint mkkey(float v, int plocal){
  uint u = __float_as_uint(v);
  u = (u & 0xFFFFFE00u) | (uint)plocal;
  return u ^ (uint)(((int)u >> 31) | 0x80000000);
}

__device__ __forceinline__ void ins3(uint& k0, uint& k1, uint& k2, uint key){
  uint t0 = k0 > key ? k0 : key;
  uint m0 = k0 > key ? key : k0;
  uint t1 = k1 > m0 ? k1 : m0;
  uint m1 = k1 > m0 ? m0 : k1;
  k2 = k2 > m1 ? k2 : m1;
  k1 = t1; k0 = t0;
}

// ---------------- K0: normalize target rows -> f32 + bf16 ----------------
__global__ __launch_bounds__(64) void k0_tn(const float* __restrict__ tf,
                                            float* __restrict__ tnf,
                                            ushort* __restrict__ tnb){
  int b = blockIdx.x, d = threadIdx.x;
  float v = tf[b * DD + d];
  float ss = v * v;
  #pragma unroll
  for (int m = 1; m < 64; m <<= 1) ss += __shfl_xor(ss, m, 64);
  float rn = 1.0f / fmaxf(sqrtf(ss), 1e-8f);
  float t = v * rn;
  tnf[b * DD + d] = t;
  tnb[b * DD + d] = f2bf(t);
}

// ---------------- K1: centers + MFMA sims + per-block top-3 --------------
__global__ __launch_bounds__(256) void k1_scan(const float* __restrict__ sp,
                                               const ushort* __restrict__ tnb,
                                               uint* __restrict__ cand){
  __shared__ ushort cn[PT * 64];        // 32 KB, XOR-swizzled bf16 centers
  __shared__ uint kbuf[4][NB][3];       // 24 KB per-wave top-3 keys
  const int tid = threadIdx.x;
  const int blk = blockIdx.x;
  const int pbase = blk * PT;
  const int plim = min(PT, PTOT - pbase);

  // phase 1: mean over T=4, normalize, store bf16 (16 threads per p)
  {
    const int s = tid & 15;
    const int pg = tid >> 4;
    for (int pass = 0; pass < 16; ++pass){
      int pl = pass * 16 + pg;
      f32x4 c = {0.f, 0.f, 0.f, 0.f};
      if (pl < plim){
        const float* base = sp + (size_t)(pbase + pl) * 256 + s * 4;
        f32x4 a0 = *(const f32x4*)(base);
        f32x4 a1 = *(const f32x4*)(base + 64);
        f32x4 a2 = *(const f32x4*)(base + 128);
        f32x4 a3 = *(const f32x4*)(base + 192);
        c = ((a0 + a1) + (a2 + a3)) * 0.25f;
      }
      float ss2 = c.x*c.x + c.y*c.y + c.z*c.z + c.w*c.w;
      ss2 += __shfl_xor(ss2, 1, 64);
      ss2 += __shfl_xor(ss2, 2, 64);
      ss2 += __shfl_xor(ss2, 4, 64);
      ss2 += __shfl_xor(ss2, 8, 64);
      float rn = 1.0f / fmaxf(sqrtf(ss2), 1e-8f);
      ushort4 h;
      h.x = f2bf(c.x * rn); h.y = f2bf(c.y * rn);
      h.z = f2bf(c.z * rn); h.w = f2bf(c.w * rn);
      int byteo = (pl * 128 + s * 8) ^ ((pl & 7) << 4);
      *(ushort4*)((char*)cn + byteo) = h;
    }
  }
  __syncthreads();

  const int wave = tid >> 6;
  const int lane = tid & 63;
  const int l15 = lane & 15;
  const int lg  = lane >> 4;
  const int wpb = wave * 64;            // this wave's 64 p's

  // A fragments (cn rows) held in registers for all 32 b-tiles
  bf16x8 afrag[4][2];
  #pragma unroll
  for (int ps = 0; ps < 4; ++ps){
    #pragma unroll
    for (int kh = 0; kh < 2; ++kh){
      int p = wpb + ps * 16 + l15;
      int byteo = (p * 128 + (kh * 32 + lg * 8) * 2) ^ ((p & 7) << 4);
      afrag[ps][kh] = *(const bf16x8*)((const char*)cn + byteo);
    }
  }

  const int lbase = lg * 4;
  for (int bt = 0; bt < 32; ++bt){
    const ushort* tp = tnb + (size_t)(bt * 16 + l15) * 64 + lg * 8;
    bf16x8 bf0 = *(const bf16x8*)(tp);
    bf16x8 bf1 = *(const bf16x8*)(tp + 32);
    f32x4 acc[4];
    #pragma unroll
    for (int ps = 0; ps < 4; ++ps){
      f32x4 z = {0.f, 0.f, 0.f, 0.f};
      acc[ps] = __builtin_amdgcn_mfma_f32_16x16x32_bf16(afrag[ps][0], bf0, z, 0, 0, 0);
      acc[ps] = __builtin_amdgcn_mfma_f32_16x16x32_bf16(afrag[ps][1], bf1, acc[ps], 0, 0, 0);
    }
    // lane-local top-3 over its 16 p-candidates (this lane's b = bt*16 + l15)
    uint k0 = 0, k1 = 0, k2 = 0;
    #pragma unroll
    for (int ps = 0; ps < 4; ++ps){
      #pragma unroll
      for (int j = 0; j < 4; ++j){
        int plocal = wpb + ps * 16 + lbase + j;
        uint key = mkkey(acc[ps][j], plocal);
        key = (plocal < plim) ? key : 0u;
        ins3(k0, k1, k2, key);
      }
    }
    // merge the 4 lanes sharing this b (xor 16, 32)
    #pragma unroll
    for (int m = 16; m <= 32; m <<= 1){
      uint o0 = (uint)__shfl_xor((int)k0, m, 64);
      uint o1 = (uint)__shfl_xor((int)k1, m, 64);
      uint o2 = (uint)__shfl_xor((int)k2, m, 64);
      ins3(k0, k1, k2, o0);
      ins3(k0, k1, k2, o1);
      ins3(k0, k1, k2, o2);
    }
    if (lane < 16){
      int b = bt * 16 + l15;
      kbuf[wave][b][0] = k0;
      kbuf[wave][b][1] = k1;
      kbuf[wave][b][2] = k2;
    }
  }
  __syncthreads();
  // merge 4 waves -> per-block top-3 per b
  for (int b = tid; b < NB; b += 256){
    uint k0 = 0, k1 = 0, k2 = 0;
    #pragma unroll
    for (int w = 0; w < 4; ++w){
      ins3(k0, k1, k2, kbuf[w][b][0]);
      ins3(k0, k1, k2, kbuf[w][b][1]);
      ins3(k0, k1, k2, kbuf[w][b][2]);
    }
    uint* dst = cand + ((size_t)b * NBLK + blk) * 3;
    dst[0] = k0; dst[1] = k1; dst[2] = k2;
  }
}

// ---------------- K2: merge pool -> top-8 -> exact fp32 re-rank ----------
__global__ __launch_bounds__(256) void k2_rerank(const uint* __restrict__ cand,
    const float* __restrict__ sp, const float* __restrict__ tnf,
    const float* __restrict__ tf, float* __restrict__ concat){
  __shared__ uint pool[NBLK * 3];
  __shared__ uint redk[4];
  __shared__ int redp[4];
  __shared__ int topp[NCAND];
  __shared__ float cen[NCAND][DD];
  __shared__ float esim[NCAND];
  __shared__ float wts[3];
  __shared__ int sel[3];
  const int b = blockIdx.x;
  const int tid = threadIdx.x;
  const int NP = NBLK * 3;
  for (int j = tid; j < NP; j += 256) pool[j] = cand[(size_t)b * NP + j];
  __syncthreads();
  const int lane = tid & 63, wave = tid >> 6;
  // 8 rounds of argmax-with-invalidate
  for (int it = 0; it < NCAND; ++it){
    uint bk = 0; int bp = 0;
    for (int j = tid; j < NP; j += 256){
      uint k = pool[j];
      if (k > bk){ bk = k; bp = j; }
    }
    #pragma unroll
    for (int m = 1; m < 64; m <<= 1){
      uint ok = (uint)__shfl_xor((int)bk, m, 64);
      int  op = __shfl_xor(bp, m, 64);
      if (ok > bk){ bk = ok; bp = op; }
    }
    if (lane == 0){ redk[wave] = bk; redp[wave] = bp; }
    __syncthreads();
    if (tid == 0){
      uint bbk = 0; int bbp = 0;
      #pragma unroll
      for (int w = 0; w < 4; ++w){
        if (redk[w] > bbk){ bbk = redk[w]; bbp = redp[w]; }
      }
      topp[it] = (bbp / 3) * PT + (int)(bbk & 0x1FFu);
      pool[bbp] = 0u;
    }
    __syncthreads();
  }
  // exact fp32 cosine sims for the 8 candidates (wave w: candidates w, w+4)
  for (int c = wave; c < NCAND; c += 4){
    int p = topp[c];
    const float* base = sp + (size_t)p * 256 + lane;
    float x = 0.25f * (base[0] + base[64] + base[128] + base[192]);
    float ss = x * x;
    float dt = x * tnf[b * DD + lane];
    #pragma unroll
    for (int m = 1; m < 64; m <<= 1){
      ss += __shfl_xor(ss, m, 64);
      dt += __shfl_xor(dt, m, 64);
    }
    cen[c][lane] = x;
    if (lane == 0) esim[c] = dt / fmaxf(sqrtf(ss), 1e-8f);
  }
  __syncthreads();
  if (tid == 0){
    float v0 = -3.0e38f, v1 = v0, v2 = v0;
    int s0 = 0, s1 = 0, s2 = 0;
    for (int c = 0; c < NCAND; ++c){
      float v = esim[c];
      if (v > v0){ v2=v1; s2=s1; v1=v0; s1=s0; v0=v; s0=c; }
      else if (v > v1){ v2=v1; s2=s1; v1=v; s1=c; }
      else if (v > v2){ v2=v; s2=c; }
    }
    float e1 = expf(v1 - v0), e2 = expf(v2 - v0);
    float inv = 1.0f / (1.0f + e1 + e2);
    wts[0] = inv; wts[1] = e1 * inv; wts[2] = e2 * inv;
    sel[0] = s0; sel[1] = s1; sel[2] = s2;
  }
  __syncthreads();
  if (tid < DD){
    float w0 = wts[0], w1 = wts[1], w2 = wts[2];
    float c0 = cen[sel[0]][tid], c1 = cen[sel[1]][tid], c2 = cen[sel[2]][tid];
    float* row = concat + (size_t)b * 192;
    row[tid]       = w0 * c0 + w1 * c1 + w2 * c2;
    row[DD + tid]  = c0;               // similar_protos[:,0] (top-1 center)
    row[128 + tid] = tf[b * DD + tid]; // raw target
  }
}

// ---------------- K3: fused MLP (L1 + LN + relu, L2 + relu, L3) ----------
__global__ __launch_bounds__(256) void k3_mlp(const float* __restrict__ concat,
    const float* __restrict__ W1, const float* __restrict__ b1,
    const float* __restrict__ lng, const float* __restrict__ lnb,
    const float* __restrict__ W2, const float* __restrict__ b2,
    const float* __restrict__ W3, const float* __restrict__ b3,
    float* __restrict__ out){
  __shared__ float cc[4][192];
  __shared__ float h1[4][256];
  __shared__ float h2[4][256];
  const int tid = threadIdx.x;
  const int rb = blockIdx.x * 4;
  for (int j = tid; j < 4 * 192; j += 256)
    cc[j / 192][j % 192] = concat[(size_t)rb * 192 + j];
  __syncthreads();
  {
    const int h = tid;
    float a0 = b1[h]; float a1 = a0, a2 = a0, a3 = a0;
    for (int k = 0; k < 192; ++k){
      float w = W1[k * 256 + h];
      a0 = fmaf(cc[0][k], w, a0);
      a1 = fmaf(cc[1][k], w, a1);
      a2 = fmaf(cc[2][k], w, a2);
      a3 = fmaf(cc[3][k], w, a3);
    }
    h1[0][h] = a0; h1[1][h] = a1; h1[2][h] = a2; h1[3][h] = a3;
  }
  __syncthreads();
  {
    const int lane = tid & 63, w = tid >> 6;   // wave w owns row w
    float v[4]; float s = 0.f, q = 0.f;
    #pragma unroll
    for (int j = 0; j < 4; ++j){
      v[j] = h1[w][lane + 64 * j];
      s += v[j]; q += v[j] * v[j];
    }
    #pragma unroll
    for (int m = 1; m < 64; m <<= 1){
      s += __shfl_xor(s, m, 64);
      q += __shfl_xor(q, m, 64);
    }
    float mu = s * (1.0f / 256.0f);
    float var = q * (1.0f / 256.0f) - mu * mu;
    float rs = rsqrtf(var + 1e-5f);
    #pragma unroll
    for (int j = 0; j < 4; ++j){
      int hh = lane + 64 * j;
      float y = (v[j] - mu) * rs * lng[hh] + lnb[hh];
      h1[w][hh] = fmaxf(y, 0.0f);
    }
  }
  __syncthreads();
  {
    const int h = tid;
    float a0 = b2[h]; float a1 = a0, a2 = a0, a3 = a0;
    for (int k = 0; k < 256; ++k){
      float w = W2[k * 256 + h];
      a0 = fmaf(h1[0][k], w, a0);
      a1 = fmaf(h1[1][k], w, a1);
      a2 = fmaf(h1[2][k], w, a2);
      a3 = fmaf(h1[3][k], w, a3);
    }
    h2[0][h] = fmaxf(a0, 0.f); h2[1][h] = fmaxf(a1, 0.f);
    h2[2][h] = fmaxf(a2, 0.f); h2[3][h] = fmaxf(a3, 0.f);
  }
  __syncthreads();
  {
    const int d = tid & 63, q = tid >> 6;      // 4 rows x 64 d
    float a = b3[d];
    for (int k = 0; k < 256; ++k)
      a = fmaf(h2[q][k], W3[k * 64 + d], a);
    out[(size_t)(rb + q) * 64 + d] = a;
  }
}

extern "C" void kernel_launch(void* const* d_in, const int* in_sizes, int n_in,
                              void* d_out, int out_size, void* d_ws, size_t ws_size,
                              hipStream_t stream){
  const float* tf = (const float*)d_in[0];
  const float* sp = (const float*)d_in[1];
  const float* W1 = (const float*)d_in[2];
  const float* b1 = (const float*)d_in[3];
  const float* lng = (const float*)d_in[4];
  const float* lnb = (const float*)d_in[5];
  const float* W2 = (const float*)d_in[6];
  const float* b2 = (const float*)d_in[7];
  const float* W3 = (const float*)d_in[8];
  const float* b3 = (const float*)d_in[9];
  float* out = (float*)d_out;

  char* ws = (char*)d_ws;
  const size_t off_tnb = 0;                 // 64 KB
  const size_t off_tnf = 65536;             // 128 KB
  const size_t off_cand = 65536 + 131072;   // 512*782*3*4 = 4804608
  const size_t off_cc = off_cand + (size_t)NB * NBLK * 3 * 4;
  const size_t need = off_cc + (size_t)NB * 192 * 4;
  if (ws_size < need) return;               // scratch too small — bail safely

  ushort* tnb = (ushort*)(ws + off_tnb);
  float* tnf = (float*)(ws + off_tnf);
  uint* cand = (uint*)(ws + off_cand);
  float* cc = (float*)(ws + off_cc);

  k0_tn<<<NB, 64, 0, stream>>>(tf, tnf, tnb);
  k1_scan<<<NBLK, 256, 0, stream>>>(sp, tnb, cand);
  k2_rerank<<<NB, 256, 0, stream>>>(cand, sp, tnf, tf, cc);
  k3_mlp<<<NB / 4, 256, 0, stream>>>(cc, W1, b1, lng, lnb, W2, b2, W3, b3, out);
}

// Round 2
// 130.355 us; speedup vs baseline: 1.0362x; 1.0362x over previous
//
#include <hip/hip_runtime.h>

#define PTOT 200000
#define NB 512
#define DD 64
#define PT 256
#define NBLK ((PTOT + PT - 1) / PT)   /* 782 */
#define NCAND 8

typedef __attribute__((ext_vector_type(4))) float f32x4;
typedef __attribute__((ext_vector_type(8))) __bf16 bf16x8;

__device__ __forceinline__ ushort f2bf(float f){
  uint u = __float_as_uint(f);
  u += 0x7FFFu + ((u >> 16) & 1u);
  return (ushort)(u >> 16);
}

// monotonic sortable key (sign-aware version, used by fallback path)
__device__ __forceinline__ uint mkkey(float v, int plocal){
  uint u = __float_as_uint(v);
  u = (u & 0xFFFFFE00u) | (uint)plocal;
  return u ^ (uint)(((int)u >> 31) | 0x80000000);
}

__device__ __forceinline__ void ins3(uint& k0, uint& k1, uint& k2, uint key){
  uint t0 = k0 > key ? k0 : key;
  uint m0 = k0 > key ? key : k0;
  uint t1 = k1 > m0 ? k1 : m0;
  uint m1 = k1 > m0 ? m0 : k1;
  k2 = k2 > m1 ? k2 : m1;
  k1 = t1; k0 = t0;
}

// ---------------- K0: normalize target rows -> f32 + bf16 ----------------
__global__ __launch_bounds__(64) void k0_tn(const float* __restrict__ tf,
                                            float* __restrict__ tnf,
                                            ushort* __restrict__ tnb){
  int b = blockIdx.x, d = threadIdx.x;
  float v = tf[b * DD + d];
  float ss = v * v;
  #pragma unroll
  for (int m = 1; m < 64; m <<= 1) ss += __shfl_xor(ss, m, 64);
  float rn = 1.0f / fmaxf(sqrtf(ss), 1e-8f);
  float t = v * rn;
  tnf[b * DD + d] = t;
  tnb[b * DD + d] = f2bf(t);
}

// ---------------- K1a: streaming centers + normalize -> bf16 cn ----------
// 16 threads per p; each thread owns 4 d's across all T=4 rows (no cross-lane
// reduce needed for the mean). Grid covers NBLK*PT rows; pad rows zero-filled.
__global__ __launch_bounds__(256) void k1a_centers(const float* __restrict__ sp,
                                                   ushort* __restrict__ cn){
  int gid = blockIdx.x * 256 + threadIdx.x;
  int p = gid >> 4, s = gid & 15;
  f32x4 c = {0.f, 0.f, 0.f, 0.f};
  if (p < PTOT){
    const float* base = sp + (size_t)p * 256 + s * 4;
    f32x4 a0 = *(const f32x4*)(base);
    f32x4 a1 = *(const f32x4*)(base + 64);
    f32x4 a2 = *(const f32x4*)(base + 128);
    f32x4 a3 = *(const f32x4*)(base + 192);
    c = ((a0 + a1) + (a2 + a3)) * 0.25f;
  }
  float ss = c.x*c.x + c.y*c.y + c.z*c.z + c.w*c.w;
  ss += __shfl_xor(ss, 1, 64);
  ss += __shfl_xor(ss, 2, 64);
  ss += __shfl_xor(ss, 4, 64);
  ss += __shfl_xor(ss, 8, 64);
  float rn = 1.0f / fmaxf(sqrtf(ss), 1e-8f);
  ushort4 h;
  h.x = f2bf(c.x * rn); h.y = f2bf(c.y * rn);
  h.z = f2bf(c.z * rn); h.w = f2bf(c.w * rn);
  *(ushort4*)(cn + (size_t)p * 64 + s * 4) = h;
}

// ---------------- K1b: MFMA sims + per-block top-3 (no kbuf merge) -------
// Wave w owns b-tiles w*8..w*8+7 over ALL 256 p's of the block; per-lane
// persistent top-3 across p-chunks, one lg-merge per b-tile at the end.
__global__ __launch_bounds__(256) void k1b_scan(const ushort* __restrict__ cn,
                                                const ushort* __restrict__ tnb,
                                                uint* __restrict__ cand){
  __shared__ __align__(16) ushort lds[PT * 64];   // 32 KB, XOR-swizzled
  const int tid = threadIdx.x;
  const int blk = blockIdx.x;
  const int pbase = blk * PT;

  // stage cn tile: linear global read (coalesced) -> swizzled LDS write
  {
    const char* src = (const char*)(cn + (size_t)pbase * 64);
    #pragma unroll
    for (int k = 0; k < 8; ++k){
      int off = (k * 256 + tid) * 16;
      f32x4 v = *(const f32x4*)(src + off);
      int dst = off ^ (((off >> 7) & 7) << 4);
      *(f32x4*)((char*)lds + dst) = v;
    }
  }
  __syncthreads();

  const int wave = tid >> 6;
  const int lane = tid & 63;
  const int l15 = lane & 15;
  const int lg  = lane >> 4;

  uint ka[8], kb[8], kc[8];
  #pragma unroll
  for (int i = 0; i < 8; ++i){ ka[i] = 0; kb[i] = 0; kc[i] = 0; }

  for (int ch = 0; ch < 4; ++ch){
    bf16x8 afrag[4][2];
    #pragma unroll
    for (int ps = 0; ps < 4; ++ps){
      int p = ch * 64 + ps * 16 + l15;
      #pragma unroll
      for (int kh = 0; kh < 2; ++kh){
        int byteo = (p * 128 + (kh * 32 + lg * 8) * 2) ^ ((p & 7) << 4);
        afrag[ps][kh] = *(const bf16x8*)((const char*)lds + byteo);
      }
    }
    #pragma unroll
    for (int bt8 = 0; bt8 < 8; ++bt8){
      int bt = wave * 8 + bt8;
      const ushort* tp = tnb + (size_t)(bt * 16 + l15) * 64 + lg * 8;
      bf16x8 bf0 = *(const bf16x8*)(tp);
      bf16x8 bf1 = *(const bf16x8*)(tp + 32);
      #pragma unroll
      for (int ps = 0; ps < 4; ++ps){
        f32x4 z = {0.f, 0.f, 0.f, 0.f};
        f32x4 acc = __builtin_amdgcn_mfma_f32_16x16x32_bf16(afrag[ps][0], bf0, z, 0, 0, 0);
        acc = __builtin_amdgcn_mfma_f32_16x16x32_bf16(afrag[ps][1], bf1, acc, 0, 0, 0);
        #pragma unroll
        for (int j = 0; j < 4; ++j){
          int plocal = ch * 64 + ps * 16 + lg * 4 + j;
          // clamp-to-0 keys: negatives can never reach the global top-8 pool
          uint key = (__float_as_uint(fmaxf(acc[j], 0.0f)) & 0xFFFFFE00u) | (uint)plocal;
          ins3(ka[bt8], kb[bt8], kc[bt8], key);
        }
      }
    }
  }
  // merge the 4 lg groups per b, write per-block top-3 directly
  #pragma unroll
  for (int bt8 = 0; bt8 < 8; ++bt8){
    uint a0 = ka[bt8], a1 = kb[bt8], a2 = kc[bt8];
    #pragma unroll
    for (int m = 16; m <= 32; m <<= 1){
      uint o0 = (uint)__shfl_xor((int)a0, m, 64);
      uint o1 = (uint)__shfl_xor((int)a1, m, 64);
      uint o2 = (uint)__shfl_xor((int)a2, m, 64);
      ins3(a0, a1, a2, o0); ins3(a0, a1, a2, o1); ins3(a0, a1, a2, o2);
    }
    if (lane < 16){
      int b = (wave * 8 + bt8) * 16 + l15;
      uint* dst = cand + ((size_t)b * NBLK + blk) * 3;
      dst[0] = a0; dst[1] = a1; dst[2] = a2;
    }
  }
}

// ---------------- K1 (fallback, round-1 fused path) -----------------------
__global__ __launch_bounds__(256) void k1_scan(const float* __restrict__ sp,
                                               const ushort* __restrict__ tnb,
                                               uint* __restrict__ cand){
  __shared__ ushort cn[PT * 64];
  __shared__ uint kbuf[4][NB][3];
  const int tid = threadIdx.x;
  const int blk = blockIdx.x;
  const int pbase = blk * PT;
  const int plim = min(PT, PTOT - pbase);
  {
    const int s = tid & 15;
    const int pg = tid >> 4;
    for (int pass = 0; pass < 16; ++pass){
      int pl = pass * 16 + pg;
      f32x4 c = {0.f, 0.f, 0.f, 0.f};
      if (pl < plim){
        const float* base = sp + (size_t)(pbase + pl) * 256 + s * 4;
        f32x4 a0 = *(const f32x4*)(base);
        f32x4 a1 = *(const f32x4*)(base + 64);
        f32x4 a2 = *(const f32x4*)(base + 128);
        f32x4 a3 = *(const f32x4*)(base + 192);
        c = ((a0 + a1) + (a2 + a3)) * 0.25f;
      }
      float ss2 = c.x*c.x + c.y*c.y + c.z*c.z + c.w*c.w;
      ss2 += __shfl_xor(ss2, 1, 64);
      ss2 += __shfl_xor(ss2, 2, 64);
      ss2 += __shfl_xor(ss2, 4, 64);
      ss2 += __shfl_xor(ss2, 8, 64);
      float rn = 1.0f / fmaxf(sqrtf(ss2), 1e-8f);
      ushort4 h;
      h.x = f2bf(c.x * rn); h.y = f2bf(c.y * rn);
      h.z = f2bf(c.z * rn); h.w = f2bf(c.w * rn);
      int byteo = (pl * 128 + s * 8) ^ ((pl & 7) << 4);
      *(ushort4*)((char*)cn + byteo) = h;
    }
  }
  __syncthreads();
  const int wave = tid >> 6;
  const int lane = tid & 63;
  const int l15 = lane & 15;
  const int lg  = lane >> 4;
  const int wpb = wave * 64;
  bf16x8 afrag[4][2];
  #pragma unroll
  for (int ps = 0; ps < 4; ++ps){
    #pragma unroll
    for (int kh = 0; kh < 2; ++kh){
      int p = wpb + ps * 16 + l15;
      int byteo = (p * 128 + (kh * 32 + lg * 8) * 2) ^ ((p & 7) << 4);
      afrag[ps][kh] = *(const bf16x8*)((const char*)cn + byteo);
    }
  }
  const int lbase = lg * 4;
  for (int bt = 0; bt < 32; ++bt){
    const ushort* tp = tnb + (size_t)(bt * 16 + l15) * 64 + lg * 8;
    bf16x8 bf0 = *(const bf16x8*)(tp);
    bf16x8 bf1 = *(const bf16x8*)(tp + 32);
    f32x4 acc[4];
    #pragma unroll
    for (int ps = 0; ps < 4; ++ps){
      f32x4 z = {0.f, 0.f, 0.f, 0.f};
      acc[ps] = __builtin_amdgcn_mfma_f32_16x16x32_bf16(afrag[ps][0], bf0, z, 0, 0, 0);
      acc[ps] = __builtin_amdgcn_mfma_f32_16x16x32_bf16(afrag[ps][1], bf1, acc[ps], 0, 0, 0);
    }
    uint k0 = 0, k1 = 0, k2 = 0;
    #pragma unroll
    for (int ps = 0; ps < 4; ++ps){
      #pragma unroll
      for (int j = 0; j < 4; ++j){
        int plocal = wpb + ps * 16 + lbase + j;
        uint key = mkkey(acc[ps][j], plocal);
        key = (plocal < plim) ? key : 0u;
        ins3(k0, k1, k2, key);
      }
    }
    #pragma unroll
    for (int m = 16; m <= 32; m <<= 1){
      uint o0 = (uint)__shfl_xor((int)k0, m, 64);
      uint o1 = (uint)__shfl_xor((int)k1, m, 64);
      uint o2 = (uint)__shfl_xor((int)k2, m, 64);
      ins3(k0, k1, k2, o0);
      ins3(k0, k1, k2, o1);
      ins3(k0, k1, k2, o2);
    }
    if (lane < 16){
      int b = bt * 16 + l15;
      kbuf[wave][b][0] = k0;
      kbuf[wave][b][1] = k1;
      kbuf[wave][b][2] = k2;
    }
  }
  __syncthreads();
  for (int b = tid; b < NB; b += 256){
    uint k0 = 0, k1 = 0, k2 = 0;
    #pragma unroll
    for (int w = 0; w < 4; ++w){
      ins3(k0, k1, k2, kbuf[w][b][0]);
      ins3(k0, k1, k2, kbuf[w][b][1]);
      ins3(k0, k1, k2, kbuf[w][b][2]);
    }
    uint* dst = cand + ((size_t)b * NBLK + blk) * 3;
    dst[0] = k0; dst[1] = k1; dst[2] = k2;
  }
}

// ---------------- K2: merge pool -> top-8 -> exact fp32 re-rank ----------
__global__ __launch_bounds__(256) void k2_rerank(const uint* __restrict__ cand,
    const float* __restrict__ sp, const float* __restrict__ tnf,
    const float* __restrict__ tf, float* __restrict__ concat){
  __shared__ uint pool[NBLK * 3];
  __shared__ uint redk[4];
  __shared__ int redp[4];
  __shared__ int topp[NCAND];
  __shared__ float cen[NCAND][DD];
  __shared__ float esim[NCAND];
  __shared__ float wts[3];
  __shared__ int sel[3];
  const int b = blockIdx.x;
  const int tid = threadIdx.x;
  const int NP = NBLK * 3;
  for (int j = tid; j < NP; j += 256) pool[j] = cand[(size_t)b * NP + j];
  __syncthreads();
  const int lane = tid & 63, wave = tid >> 6;
  for (int it = 0; it < NCAND; ++it){
    uint bk = 0; int bp = 0;
    for (int j = tid; j < NP; j += 256){
      uint k = pool[j];
      if (k > bk){ bk = k; bp = j; }
    }
    #pragma unroll
    for (int m = 1; m < 64; m <<= 1){
      uint ok = (uint)__shfl_xor((int)bk, m, 64);
      int  op = __shfl_xor(bp, m, 64);
      if (ok > bk){ bk = ok; bp = op; }
    }
    if (lane == 0){ redk[wave] = bk; redp[wave] = bp; }
    __syncthreads();
    if (tid == 0){
      uint bbk = 0; int bbp = 0;
      #pragma unroll
      for (int w = 0; w < 4; ++w){
        if (redk[w] > bbk){ bbk = redk[w]; bbp = redp[w]; }
      }
      int p = (bbp / 3) * PT + (int)(bbk & 0x1FFu);
      topp[it] = min(p, PTOT - 1);   // belt-and-suspenders vs pad keys
      pool[bbp] = 0u;
    }
    __syncthreads();
  }
  for (int c = wave; c < NCAND; c += 4){
    int p = topp[c];
    const float* base = sp + (size_t)p * 256 + lane;
    float x = 0.25f * (base[0] + base[64] + base[128] + base[192]);
    float ss = x * x;
    float dt = x * tnf[b * DD + lane];
    #pragma unroll
    for (int m = 1; m < 64; m <<= 1){
      ss += __shfl_xor(ss, m, 64);
      dt += __shfl_xor(dt, m, 64);
    }
    cen[c][lane] = x;
    if (lane == 0) esim[c] = dt / fmaxf(sqrtf(ss), 1e-8f);
  }
  __syncthreads();
  if (tid == 0){
    float v0 = -3.0e38f, v1 = v0, v2 = v0;
    int s0 = 0, s1 = 0, s2 = 0;
    for (int c = 0; c < NCAND; ++c){
      float v = esim[c];
      if (v > v0){ v2=v1; s2=s1; v1=v0; s1=s0; v0=v; s0=c; }
      else if (v > v1){ v2=v1; s2=s1; v1=v; s1=c; }
      else if (v > v2){ v2=v; s2=c; }
    }
    float e1 = expf(v1 - v0), e2 = expf(v2 - v0);
    float inv = 1.0f / (1.0f + e1 + e2);
    wts[0] = inv; wts[1] = e1 * inv; wts[2] = e2 * inv;
    sel[0] = s0; sel[1] = s1; sel[2] = s2;
  }
  __syncthreads();
  if (tid < DD){
    float w0 = wts[0], w1 = wts[1], w2 = wts[2];
    float c0 = cen[sel[0]][tid], c1 = cen[sel[1]][tid], c2 = cen[sel[2]][tid];
    float* row = concat + (size_t)b * 192;
    row[tid]       = w0 * c0 + w1 * c1 + w2 * c2;
    row[DD + tid]  = c0;
    row[128 + tid] = tf[b * DD + tid];
  }
}

// ---------------- K3: fused MLP (L1 + LN + relu, L2 + relu, L3) ----------
__global__ __launch_bounds__(256) void k3_mlp(const float* __restrict__ concat,
    const float* __restrict__ W1, const float* __restrict__ b1,
    const float* __restrict__ lng, const float* __restrict__ lnb,
    const float* __restrict__ W2, const float* __restrict__ b2,
    const float* __restrict__ W3, const float* __restrict__ b3,
    float* __restrict__ out){
  __shared__ float cc[4][192];
  __shared__ float h1[4][256];
  __shared__ float h2[4][256];
  const int tid = threadIdx.x;
  const int rb = blockIdx.x * 4;
  for (int j = tid; j < 4 * 192; j += 256)
    cc[j / 192][j % 192] = concat[(size_t)rb * 192 + j];
  __syncthreads();
  {
    const int h = tid;
    float a0 = b1[h]; float a1 = a0, a2 = a0, a3 = a0;
    for (int k = 0; k < 192; ++k){
      float w = W1[k * 256 + h];
      a0 = fmaf(cc[0][k], w, a0);
      a1 = fmaf(cc[1][k], w, a1);
      a2 = fmaf(cc[2][k], w, a2);
      a3 = fmaf(cc[3][k], w, a3);
    }
    h1[0][h] = a0; h1[1][h] = a1; h1[2][h] = a2; h1[3][h] = a3;
  }
  __syncthreads();
  {
    const int lane = tid & 63, w = tid >> 6;
    float v[4]; float s = 0.f, q = 0.f;
    #pragma unroll
    for (int j = 0; j < 4; ++j){
      v[j] = h1[w][lane + 64 * j];
      s += v[j]; q += v[j] * v[j];
    }
    #pragma unroll
    for (int m = 1; m < 64; m <<= 1){
      s += __shfl_xor(s, m, 64);
      q += __shfl_xor(q, m, 64);
    }
    float mu = s * (1.0f / 256.0f);
    float var = q * (1.0f / 256.0f) - mu * mu;
    float rs = rsqrtf(var + 1e-5f);
    #pragma unroll
    for (int j = 0; j < 4; ++j){
      int hh = lane + 64 * j;
      float y = (v[j] - mu) * rs * lng[hh] + lnb[hh];
      h1[w][hh] = fmaxf(y, 0.0f);
    }
  }
  __syncthreads();
  {
    const int h = tid;
    float a0 = b2[h]; float a1 = a0, a2 = a0, a3 = a0;
    for (int k = 0; k < 256; ++k){
      float w = W2[k * 256 + h];
      a0 = fmaf(h1[0][k], w, a0);
      a1 = fmaf(h1[1][k], w, a1);
      a2 = fmaf(h1[2][k], w, a2);
      a3 = fmaf(h1[3][k], w, a3);
    }
    h2[0][h] = fmaxf(a0, 0.f); h2[1][h] = fmaxf(a1, 0.f);
    h2[2][h] = fmaxf(a2, 0.f); h2[3][h] = fmaxf(a3, 0.f);
  }
  __syncthreads();
  {
    const int d = tid & 63, q = tid >> 6;
    float a = b3[d];
    for (int k = 0; k < 256; ++k)
      a = fmaf(h2[q][k], W3[k * 64 + d], a);
    out[(size_t)(rb + q) * 64 + d] = a;
  }
}

extern "C" void kernel_launch(void* const* d_in, const int* in_sizes, int n_in,
                              void* d_out, int out_size, void* d_ws, size_t ws_size,
                              hipStream_t stream){
  const float* tf = (const float*)d_in[0];
  const float* sp = (const float*)d_in[1];
  const float* W1 = (const float*)d_in[2];
  const float* b1 = (const float*)d_in[3];
  const float* lng = (const float*)d_in[4];
  const float* lnb = (const float*)d_in[5];
  const float* W2 = (const float*)d_in[6];
  const float* b2 = (const float*)d_in[7];
  const float* W3 = (const float*)d_in[8];
  const float* b3 = (const float*)d_in[9];
  float* out = (float*)d_out;

  char* ws = (char*)d_ws;
  const size_t off_tnb  = 0;                                   // 64 KB
  const size_t off_tnf  = 65536;                               // 128 KB
  const size_t off_cn   = 65536 + 131072;                      // 25.6 MB (bf16 centers, padded)
  const size_t cn_bytes = (size_t)NBLK * PT * 64 * 2;
  const size_t off_cand = off_cn + cn_bytes;
  const size_t off_cc   = off_cand + (size_t)NB * NBLK * 3 * 4;
  const size_t need_new = off_cc + (size_t)NB * 192 * 4;

  // fallback (fused, no cn materialization) layout
  const size_t f_off_cand = 65536 + 131072;
  const size_t f_off_cc   = f_off_cand + (size_t)NB * NBLK * 3 * 4;
  const size_t need_old   = f_off_cc + (size_t)NB * 192 * 4;

  ushort* tnb = (ushort*)(ws + off_tnb);
  float* tnf = (float*)(ws + off_tnf);

  if (ws_size >= need_new){
    ushort* cnb = (ushort*)(ws + off_cn);
    uint* cand = (uint*)(ws + off_cand);
    float* cc = (float*)(ws + off_cc);
    k0_tn<<<NB, 64, 0, stream>>>(tf, tnf, tnb);
    k1a_centers<<<(NBLK * PT) / 16, 256, 0, stream>>>(sp, cnb);
    k1b_scan<<<NBLK, 256, 0, stream>>>(cnb, tnb, cand);
    k2_rerank<<<NB, 256, 0, stream>>>(cand, sp, tnf, tf, cc);
    k3_mlp<<<NB / 4, 256, 0, stream>>>(cc, W1, b1, lng, lnb, W2, b2, W3, b3, out);
  } else if (ws_size >= need_old){
    uint* cand = (uint*)(ws + f_off_cand);
    float* cc = (float*)(ws + f_off_cc);
    k0_tn<<<NB, 64, 0, stream>>>(tf, tnf, tnb);
    k1_scan<<<NBLK, 256, 0, stream>>>(sp, tnb, cand);
    k2_rerank<<<NB, 256, 0, stream>>>(cand, sp, tnf, tf, cc);
    k3_mlp<<<NB / 4, 256, 0, stream>>>(cc, W1, b1, lng, lnb, W2, b2, W3, b3, out);
  }
}